// Round 1
// baseline (147.406 us; speedup 1.0000x reference)
//
#include <hip/hip_runtime.h>
#include <math.h>

#define VOCAB   32000
#define BLTOT   128    // B*L
#define HTOT    64     // H = 8 heads * 8 hph
#define BLT     16     // bl rows accumulated per thread
#define VPB     256    // vocab rows per block (= threads per block)

// ---------------------------------------------------------------------------
// Prep: build interleaved uniform table in ws:
//   ws[bl*128 + jj*8 + u]     = freqs[bl*64 + jj*4 + u]
//   ws[bl*128 + jj*8 + 4 + u] = amps * cos(phases - ip[j]) * W[j/8]
// 64 KB total; block-uniform reads in the main kernel -> s_load.
// ---------------------------------------------------------------------------
__global__ void prep_kernel(const float* __restrict__ freqs,
                            const float* __restrict__ amps,
                            const float* __restrict__ phases,
                            const float* __restrict__ ip,
                            const float* __restrict__ W,
                            float* __restrict__ ws) {
    int t = blockIdx.x * blockDim.x + threadIdx.x;   // 0 .. 8191
    if (t >= BLTOT * HTOT) return;
    int bl = t >> 6;
    int j  = t & 63;
    float f  = freqs[t];
    float cw = amps[t] * cosf(phases[t] - ip[j]) * W[j >> 3];
    int jj = j >> 2, u = j & 3;
    ws[bl * 128 + jj * 8 + u]     = f;
    ws[bl * 128 + jj * 8 + 4 + u] = cw;
}

// ---------------------------------------------------------------------------
// Main: thread owns one vocab row v, accumulates BLT=16 (b,l) outputs in
// registers. vocab_patterns float4 loaded once per (v, jj), reused 16x.
// (bl,j) data comes from the uniform table via scalar loads.
// ---------------------------------------------------------------------------
__global__ __launch_bounds__(VPB) void
wave_main(const float* __restrict__ vp,     // vocab_patterns, VOCAB x 64
          const float* __restrict__ uni,    // ws table
          const float* __restrict__ bptr,   // bias (1 elem)
          float* __restrict__ out) {        // (B*L, VOCAB)
    const int v   = blockIdx.x * VPB + threadIdx.x;   // 32000 = 125*256 exact
    const int bl0 = blockIdx.y * BLT;                 // 128 = 8*16 exact

    const float4* __restrict__ vp4 = (const float4*)vp;
    const float4* __restrict__ u4  = (const float4*)uni;

    float acc[BLT];
#pragma unroll
    for (int i = 0; i < BLT; ++i) acc[i] = 0.0f;

#pragma unroll 4
    for (int jj = 0; jj < 16; ++jj) {
        const float4 vf = vp4[v * 16 + jj];           // per-thread vector load
#pragma unroll
        for (int i = 0; i < BLT; ++i) {
            // block-uniform addresses -> scalar loads (s_load_dwordx4 x2)
            const float4 f4  = u4[(bl0 + i) * 32 + jj * 2];
            const float4 cw4 = u4[(bl0 + i) * 32 + jj * 2 + 1];
            acc[i] = fmaf(cw4.x, __expf(-fabsf(f4.x - vf.x)), acc[i]);
            acc[i] = fmaf(cw4.y, __expf(-fabsf(f4.y - vf.y)), acc[i]);
            acc[i] = fmaf(cw4.z, __expf(-fabsf(f4.z - vf.z)), acc[i]);
            acc[i] = fmaf(cw4.w, __expf(-fabsf(f4.w - vf.w)), acc[i]);
        }
    }

    const float b0 = bptr[0];
#pragma unroll
    for (int i = 0; i < BLT; ++i)
        out[(bl0 + i) * VOCAB + v] = acc[i] + b0;     // coalesced stores
}

extern "C" void kernel_launch(void* const* d_in, const int* in_sizes, int n_in,
                              void* d_out, int out_size, void* d_ws, size_t ws_size,
                              hipStream_t stream) {
    const float* freqs  = (const float*)d_in[0];
    const float* amps   = (const float*)d_in[1];
    const float* phases = (const float*)d_in[2];
    const float* vp     = (const float*)d_in[3];
    const float* ip     = (const float*)d_in[4];
    const float* W      = (const float*)d_in[5];
    const float* b      = (const float*)d_in[6];
    float* out = (float*)d_out;
    float* ws  = (float*)d_ws;   // needs 64 KB

    // 1) build uniform {f, cw} table
    prep_kernel<<<dim3(32), dim3(256), 0, stream>>>(freqs, amps, phases, ip, W, ws);

    // 2) main interference kernel: 125 vocab tiles x 8 bl-groups
    wave_main<<<dim3(VOCAB / VPB, BLTOT / BLT), dim3(VPB), 0, stream>>>(vp, ws, b, out);
}